// Round 15
// baseline (2510.590 us; speedup 1.0000x reference)
//
#include <hip/hip_runtime.h>

// Problem constants: B=8, N=16384, NPOINT=1024, NSAMPLE=32, RADIUS=0.4, C_IN=64
#define R2 0.16f  // f32-nearest of python 0.4*0.4 (== nearest f32 to 0.16)

typedef float f32x2 __attribute__((ext_vector_type(2)));

// Exact (non-contracted) squared distance for ball query.
__device__ __forceinline__ float sqd(float x, float y, float z,
                                     float px, float py, float pz) {
  float dx = __fsub_rn(x, px);
  float dy = __fsub_rn(y, py);
  float dz = __fsub_rn(z, pz);
  return __fadd_rn(__fadd_rn(__fmul_rn(dx, dx), __fmul_rn(dy, dy)),
                   __fmul_rn(dz, dz));
}

// Canonical gfx9 wave64 max-reduce via DPP (verified R12-R14).
// Full-wave max valid in lane 63.
__device__ __forceinline__ float wave64_max_dpp(float x) {
#define DPP_STEP(CTRL)                                                      \
  {                                                                         \
    int t_ = __builtin_amdgcn_update_dpp(__float_as_int(x),                 \
                                         __float_as_int(x), CTRL, 0xf, 0xf, \
                                         false);                            \
    x = fmaxf(x, __int_as_float(t_));                                       \
  }
  DPP_STEP(0x111)  // row_shr:1
  DPP_STEP(0x112)  // row_shr:2
  DPP_STEP(0x114)  // row_shr:4
  DPP_STEP(0x118)  // row_shr:8
  DPP_STEP(0x142)  // row_bcast:15
  DPP_STEP(0x143)  // row_bcast:31
#undef DPP_STEP
  return x;
}

// ---------------- SoA staging: xyz (B,N,3) -> xs/ys/zs (B,N) ----------------
__global__ __launch_bounds__(256) void soa_kernel(const float* __restrict__ xyz,
                                                  float* __restrict__ xs,
                                                  float* __restrict__ ys,
                                                  float* __restrict__ zs) {
  int t = blockIdx.x * 256 + threadIdx.x;  // 0 .. 131071 = (b,n)
  const float* p = xyz + (size_t)t * 3;
  xs[t] = p[0];
  ys[t] = p[1];
  zs[t] = p[2];
}

// ---------------- FPS: one block (1024 thr) per batch, 16 pts/thread ---------
// ONE barrier per iteration (R14 post-mortem: the two 16-wave barriers + the
// serial post-barrier rescan/atomicMin chain dominate, not the sweep).
// Pre-barrier per wave: DPP wave max -> readlane(63) SGPR broadcast -> lane0
// atomicMax(s_vmax[sl]); ballot picks lowest matching lane (contiguous
// ownership: lane order == gid order), that lane rescans its M regs (static
// descending chain) and writes {val,gid,x,y,z} to s_slot[sl][wid]. Every wave
// writes its slot every iter -> no stale entries.
// Post-barrier: v = s_vmax[sl]; lanes 0-15 read slot vals (stride 9 ->
// conflict-free); ballot(val==v)+ctz = lowest wid = lowest gid (exact
// tie-break); winner slot read broadcast -> next px,py,pz + index.
// s_vmax 3-rotation, reset 2-ahead post-barrier: writers of slot (it+2)%3 are
// after barrier(it+1); readers of its old value are before barrier(it). Safe.
__global__ __launch_bounds__(1024) void fps_kernel(
    const float* __restrict__ xyz, const float* __restrict__ xs,
    const float* __restrict__ ys, const float* __restrict__ zs,
    int* __restrict__ idx_out) {
#pragma clang fp contract(off)
  extern __shared__ float4 xylds[];  // 8192 entries = 128 KB
  __shared__ unsigned s_vmax[3];
  __shared__ unsigned s_slot[3][16 * 9];  // [rot][wid*9 + {val,gid,x,y,z}]
  int b = blockIdx.x;
  int tid = threadIdx.x;
  int lane = tid & 63, wid = tid >> 6;
  const float* xb = xyz + (size_t)b * 16384 * 3;
  int base = tid << 4;  // 16 consecutive points per thread
  const float4* xv = (const float4*)(xs + (size_t)b * 16384 + base);
  const float4* yv = (const float4*)(ys + (size_t)b * 16384 + base);
  const float4* zv = (const float4*)(zs + (size_t)b * 16384 + base);
  float xr[16], yr[16], zr[16];
#pragma unroll
  for (int q = 0; q < 4; ++q) {
    *(float4*)(xr + 4 * q) = xv[q];
    *(float4*)(yr + 4 * q) = yv[q];
    *(float4*)(zr + 4 * q) = zv[q];
  }
  f32x2 Z[8], M[8];
#pragma unroll
  for (int q = 0; q < 8; ++q) {
    xylds[(q << 10) + tid] =
        make_float4(xr[2 * q], xr[2 * q + 1], yr[2 * q], yr[2 * q + 1]);
    Z[q] = {zr[2 * q], zr[2 * q + 1]};
    M[q] = {__builtin_inff(), __builtin_inff()};
  }
  if (tid == 0) idx_out[b * 1024] = 0;
  if (tid < 3) s_vmax[tid] = 0u;
  __syncthreads();
  float px = xb[0], py = xb[1], pz = xb[2];
  int sl = 1, slp2 = 0;  // sl = it%3, slp2 = (it+2)%3
  for (int it = 1; it < 1024; ++it) {
    // ---- packed sweep: native f32x2 ops, no FMA (contract off)
    f32x2 px2 = {px, px}, py2 = {py, py}, pz2 = {pz, pz};
    float tv = -1.0f;
#pragma unroll
    for (int q = 0; q < 8; ++q) {
      float4 t = xylds[(q << 10) + tid];  // {x0,x1,y0,y1}
      f32x2 X = {t.x, t.y};
      f32x2 Y = {t.z, t.w};
      f32x2 dx = X - px2;
      f32x2 dy = Y - py2;
      f32x2 dz = Z[q] - pz2;
      f32x2 d = dx * dx + dy * dy + dz * dz;  // ((dx2+dy2)+dz2), RN each op
      M[q].x = fminf(M[q].x, d.x);
      M[q].y = fminf(M[q].y, d.y);
      tv = fmaxf(fmaxf(tv, M[q].x), M[q].y);  // fuses to v_max3
    }
    // ---- wave candidate (pre-barrier, wave-parallel)
    float bv = wave64_max_dpp(tv);
    unsigned bvb = (unsigned)__builtin_amdgcn_readlane(__float_as_int(bv), 63);
    float bvf = __int_as_float((int)bvb);
    if (lane == 0) atomicMax(&s_vmax[sl], bvb);
    unsigned long long mk = __ballot(tv == bvf);
    int wlane = (int)__builtin_ctzll(mk);
    if (lane == wlane) {
      // lowest k achieving bvf + its coords, static descending chain
      int k = 0;
      float wx = 0.0f, wy = 0.0f, wz = 0.0f;
#pragma unroll
      for (int q = 7; q >= 0; --q) {
        float4 t = xylds[(q << 10) + tid];
        if (M[q].y == bvf) { k = 2 * q + 1; wx = t.y; wy = t.w; wz = Z[q].y; }
        if (M[q].x == bvf) { k = 2 * q;     wx = t.x; wy = t.z; wz = Z[q].x; }
      }
      unsigned* sp = &s_slot[sl][wid * 9];
      sp[0] = bvb;
      sp[1] = (unsigned)(base + k);
      sp[2] = (unsigned)__float_as_int(wx);
      sp[3] = (unsigned)__float_as_int(wy);
      sp[4] = (unsigned)__float_as_int(wz);
    }
    __syncthreads();  // the only barrier
    unsigned v = s_vmax[sl];
    if (tid == 0) s_vmax[slp2] = 0u;  // reset 2-ahead (ordering: see header)
    // ---- block winner: lowest wid whose slot val == v (== lowest gid)
    unsigned sval = s_slot[sl][(lane & 15) * 9];
    unsigned long long m2 = __ballot(sval == v);
    int w2 = (int)__builtin_ctzll(m2);
    const unsigned* wp = &s_slot[sl][w2 * 9];
    int j = (int)wp[1];
    px = __int_as_float((int)wp[2]);
    py = __int_as_float((int)wp[3]);
    pz = __int_as_float((int)wp[4]);
    if (tid == 0) idx_out[b * 1024 + it] = j;
    sl = (sl == 2) ? 0 : sl + 1;
    slp2 = (slp2 == 2) ? 0 : slp2 + 1;
  }
}

// ---------------- gather new_xyz into d_out[0 .. 24576) ----------------------
__global__ __launch_bounds__(256) void gather_newxyz(const float* __restrict__ xyz,
                                                     const int* __restrict__ idx,
                                                     float* __restrict__ out) {
  int t = blockIdx.x * 256 + threadIdx.x;  // 0..8191 = (b,p)
  int b = t >> 10;
  int i = idx[t];
  const float* src = xyz + ((size_t)b * 16384 + i) * 3;
  float* dst = out + (size_t)t * 3;
  dst[0] = src[0];
  dst[1] = src[1];
  dst[2] = src[2];
}

// ---------------- transpose features (B,64,N) -> (B,N,64) --------------------
__global__ __launch_bounds__(256) void transpose_feats(const float* __restrict__ f,
                                                       float* __restrict__ fT) {
  __shared__ float tile[64][65];
  int b = blockIdx.x >> 8;
  int n0 = (blockIdx.x & 255) << 6;
  int t = threadIdx.x;
  int nn = t & 63, c0 = t >> 6;
#pragma unroll
  for (int r = 0; r < 64; r += 4) {
    int c = c0 + r;
    tile[c][nn] = f[((size_t)b * 64 + c) * 16384 + n0 + nn];
  }
  __syncthreads();
  int cc = t & 63, n1 = t >> 6;
#pragma unroll
  for (int r = 0; r < 64; r += 4) {
    int n = n1 + r;
    fT[((size_t)b * 16384 + n0 + n) * 64 + cc] = tile[cc][n];
  }
}

// ---------------- ball query: one wave per centroid --------------------------
__global__ __launch_bounds__(256) void ballquery_kernel(const float* __restrict__ xyz,
                                                        const float* __restrict__ newxyz,
                                                        int* __restrict__ gidx) {
  int wid = threadIdx.x >> 6, lane = threadIdx.x & 63;
  int cid = blockIdx.x * 4 + wid;  // 0..8191
  int b = cid >> 10;
  const float* xb = xyz + (size_t)b * 16384 * 3;
  float cx = newxyz[cid * 3 + 0];
  float cy = newxyz[cid * 3 + 1];
  float cz = newxyz[cid * 3 + 2];
  int* out = gidx + (size_t)cid * 32;
  int found = 0;
  int first = -1;
  for (int c0 = 0; c0 < 16384; c0 += 64) {
    int g = c0 + lane;
    float xx = xb[g * 3 + 0], yy = xb[g * 3 + 1], zz = xb[g * 3 + 2];
    float d2 = sqd(xx, yy, zz, cx, cy, cz);
    bool inr = (d2 <= R2);
    unsigned long long mask = __ballot(inr);
    if (first < 0 && mask) first = c0 + (int)__builtin_ctzll(mask);
    int pre = __popcll(mask & ((1ull << lane) - 1ull));
    int slot = found + pre;
    if (inr && slot < 32) out[slot] = g;
    found += __popcll(mask);
    if (found >= 32) break;
  }
  for (int s = found + lane; s < 32; s += 64) out[s] = first;
}

// ---------------- fused group + MLP(67->64->64->128) + maxpool ---------------
#define FMA16(BASEPTR)                                                     \
  do {                                                                     \
    const float4* hp_ = (const float4*)(BASEPTR);                          \
    float4 v0 = hp_[0], v1 = hp_[1], v2 = hp_[2], v3 = hp_[3];             \
    float a = acc[s];                                                      \
    a = fmaf(w[0], v0.x, a);  a = fmaf(w[1], v0.y, a);                     \
    a = fmaf(w[2], v0.z, a);  a = fmaf(w[3], v0.w, a);                     \
    a = fmaf(w[4], v1.x, a);  a = fmaf(w[5], v1.y, a);                     \
    a = fmaf(w[6], v1.z, a);  a = fmaf(w[7], v1.w, a);                     \
    a = fmaf(w[8], v2.x, a);  a = fmaf(w[9], v2.y, a);                     \
    a = fmaf(w[10], v2.z, a); a = fmaf(w[11], v2.w, a);                    \
    a = fmaf(w[12], v3.x, a); a = fmaf(w[13], v3.y, a);                    \
    a = fmaf(w[14], v3.z, a); a = fmaf(w[15], v3.w, a);                    \
    acc[s] = a;                                                            \
  } while (0)

__global__ __launch_bounds__(256) void mlp_kernel(
    const float* __restrict__ xyz, const float* __restrict__ feats,
    const float* __restrict__ featsT, const float* __restrict__ newxyz,
    const int* __restrict__ gidx,
    const float* __restrict__ W1, const float* __restrict__ b1,
    const float* __restrict__ W2, const float* __restrict__ b2,
    const float* __restrict__ W3, const float* __restrict__ b3,
    float* __restrict__ out, int useT) {
  __shared__ float buf[4][32 * 68];
  int wid = threadIdx.x >> 6, lane = threadIdx.x & 63;
  int cid = blockIdx.x * 4 + wid;
  int b = cid >> 10, p = cid & 1023;
  float* A = buf[wid];
  const int* gi = gidx + (size_t)cid * 32;
  float cx = newxyz[cid * 3 + 0];
  float cy = newxyz[cid * 3 + 1];
  float cz = newxyz[cid * 3 + 2];

  // ---- stage h0
  if (useT) {
    const float4* fT4 = (const float4*)(featsT + (size_t)b * 16384 * 64);
    for (int t = lane; t < 512; t += 64) {
      int s = t >> 4, q = t & 15;
      int g = gi[s];
      float4 v = fT4[(size_t)g * 16 + q];
      *(float4*)(A + s * 68 + q * 4) = v;
    }
  } else {
    const float* fb = feats + (size_t)b * 64 * 16384;
    for (int t = lane; t < 2048; t += 64) {
      int c = t >> 5, s = t & 31;
      int g = gi[s];
      A[s * 68 + c] = fb[(size_t)c * 16384 + g];
    }
  }
  for (int t = lane; t < 96; t += 64) {
    int s = t / 3, c = t - s * 3;
    int g = gi[s];
    float pv = xyz[((size_t)b * 16384 + g) * 3 + c];
    float cv = (c == 0) ? cx : ((c == 1) ? cy : cz);
    A[s * 68 + 64 + c] = __fsub_rn(pv, cv);
  }
  if (lane < 32) A[lane * 68 + 67] = 0.0f;
  __syncthreads();

  int o = lane;
  float acc[32];

  // ---- L1: 67 -> 64
#pragma unroll
  for (int s = 0; s < 32; ++s) acc[s] = b1[o];
  {
    const float* wr = W1 + o * 67;
    for (int cb = 0; cb < 4; ++cb) {
      float w[16];
#pragma unroll
      for (int q = 0; q < 16; ++q) w[q] = wr[3 + cb * 16 + q];
#pragma unroll
      for (int s = 0; s < 32; ++s) { FMA16(A + s * 68 + cb * 16); }
    }
    float w0 = wr[0], w1 = wr[1], w2 = wr[2];
#pragma unroll
    for (int s = 0; s < 32; ++s) {
      float a = acc[s];
      a = fmaf(w0, A[s * 68 + 64], a);
      a = fmaf(w1, A[s * 68 + 65], a);
      a = fmaf(w2, A[s * 68 + 66], a);
      acc[s] = a;
    }
  }
  __syncthreads();
#pragma unroll
  for (int s = 0; s < 32; ++s) A[s * 64 + o] = fmaxf(acc[s], 0.0f);
  __syncthreads();

  // ---- L2: 64 -> 64
#pragma unroll
  for (int s = 0; s < 32; ++s) acc[s] = b2[o];
  {
    const float* wr = W2 + o * 64;
    for (int cb = 0; cb < 4; ++cb) {
      float w[16];
#pragma unroll
      for (int q = 0; q < 16; ++q) w[q] = wr[cb * 16 + q];
#pragma unroll
      for (int s = 0; s < 32; ++s) { FMA16(A + s * 64 + cb * 16); }
    }
  }
  __syncthreads();
#pragma unroll
  for (int s = 0; s < 32; ++s) A[s * 64 + o] = fmaxf(acc[s], 0.0f);
  __syncthreads();

  // ---- L3: 64 -> 128, fused relu + maxpool over s
  float* outp = out + 24576;
  for (int po = 0; po < 2; ++po) {
    int o2 = lane + (po << 6);
#pragma unroll
    for (int s = 0; s < 32; ++s) acc[s] = b3[o2];
    const float* wr = W3 + o2 * 64;
    for (int cb = 0; cb < 4; ++cb) {
      float w[16];
#pragma unroll
      for (int q = 0; q < 16; ++q) w[q] = wr[cb * 16 + q];
#pragma unroll
      for (int s = 0; s < 32; ++s) { FMA16(A + s * 64 + cb * 16); }
    }
    float mx = 0.0f;  // relu floor
#pragma unroll
    for (int s = 0; s < 32; ++s) mx = fmaxf(mx, acc[s]);
    outp[((size_t)b * 128 + o2) * 1024 + p] = mx;
  }
}

extern "C" void kernel_launch(void* const* d_in, const int* in_sizes, int n_in,
                              void* d_out, int out_size, void* d_ws, size_t ws_size,
                              hipStream_t stream) {
  const float* xyz = (const float*)d_in[0];
  const float* feats = (const float*)d_in[1];
  const float* W1 = (const float*)d_in[2];
  const float* b1 = (const float*)d_in[3];
  const float* W2 = (const float*)d_in[4];
  const float* b2 = (const float*)d_in[5];
  const float* W3 = (const float*)d_in[6];
  const float* b3 = (const float*)d_in[7];
  float* out = (float*)d_out;

  // ws layout: idx 32K | gidx 1M | xs/ys/zs 1.5M | featsT 32M (optional)
  int* idx = (int*)d_ws;
  int* gidx = (int*)((char*)d_ws + 32768);
  float* xs = (float*)((char*)d_ws + 32768 + 1048576);
  float* ys = xs + 131072;
  float* zs = ys + 131072;
  float* featsT = (float*)((char*)d_ws + 32768 + 1048576 + 1572864);
  size_t needT = 32768 + 1048576 + 1572864 +
                 (size_t)8 * 16384 * 64 * sizeof(float);
  int useT = (ws_size >= needT) ? 1 : 0;

  soa_kernel<<<512, 256, 0, stream>>>(xyz, xs, ys, zs);
  fps_kernel<<<8, 1024, 131072, stream>>>(xyz, xs, ys, zs, idx);
  gather_newxyz<<<32, 256, 0, stream>>>(xyz, idx, out);
  if (useT) transpose_feats<<<2048, 256, 0, stream>>>(feats, featsT);
  ballquery_kernel<<<2048, 256, 0, stream>>>(xyz, out, gidx);
  mlp_kernel<<<2048, 256, 0, stream>>>(xyz, feats, featsT, out, gidx,
                                       W1, b1, W2, b2, W3, b3, out, useT);
}

// Round 16
// 2203.327 us; speedup vs baseline: 1.1395x; 1.1395x over previous
//
#include <hip/hip_runtime.h>

// Problem constants: B=8, N=16384, NPOINT=1024, NSAMPLE=32, RADIUS=0.4, C_IN=64
#define R2 0.16f  // f32-nearest of python 0.4*0.4 (== nearest f32 to 0.16)

typedef float f32x2 __attribute__((ext_vector_type(2)));

// Exact (non-contracted) squared distance for ball query.
__device__ __forceinline__ float sqd(float x, float y, float z,
                                     float px, float py, float pz) {
  float dx = __fsub_rn(x, px);
  float dy = __fsub_rn(y, py);
  float dz = __fsub_rn(z, pz);
  return __fadd_rn(__fadd_rn(__fmul_rn(dx, dx), __fmul_rn(dy, dy)),
                   __fmul_rn(dz, dz));
}

// Canonical gfx9 wave64 reduce via DPP (verified R12-R15). Valid in lane 63.
__device__ __forceinline__ float wave64_max_dpp(float x) {
#define DPP_STEP(CTRL)                                                      \
  {                                                                         \
    int t_ = __builtin_amdgcn_update_dpp(__float_as_int(x),                 \
                                         __float_as_int(x), CTRL, 0xf, 0xf, \
                                         false);                            \
    x = fmaxf(x, __int_as_float(t_));                                       \
  }
  DPP_STEP(0x111) DPP_STEP(0x112) DPP_STEP(0x114)
  DPP_STEP(0x118) DPP_STEP(0x142) DPP_STEP(0x143)
#undef DPP_STEP
  return x;
}
__device__ __forceinline__ unsigned wave64_min_dpp_u32(unsigned x) {
#define DPP_STEP(CTRL)                                                      \
  {                                                                         \
    unsigned t_ = (unsigned)__builtin_amdgcn_update_dpp(                    \
        (int)x, (int)x, CTRL, 0xf, 0xf, false);                             \
    x = (t_ < x) ? t_ : x;                                                  \
  }
  DPP_STEP(0x111) DPP_STEP(0x112) DPP_STEP(0x114)
  DPP_STEP(0x118) DPP_STEP(0x142) DPP_STEP(0x143)
#undef DPP_STEP
  return x;
}

// ---------------- counting sort by 8x8x8 grid cell (per batch) ---------------
__global__ __launch_bounds__(256) void zero_hist(unsigned* __restrict__ h) {
  h[blockIdx.x * 256 + threadIdx.x] = 0u;  // grid 16 -> 4096 entries
}

__global__ __launch_bounds__(256) void hist_kernel(const float* __restrict__ xyz,
                                                   unsigned* __restrict__ hist,
                                                   unsigned* __restrict__ rank,
                                                   unsigned* __restrict__ cid) {
  int t = blockIdx.x * 256 + threadIdx.x;  // 0..131071 = (b,n)
  int b = t >> 14;
  const float* p = xyz + (size_t)t * 3;
  int cx = (int)floorf(p[0] + 4.0f);
  int cy = (int)floorf(p[1] + 4.0f);
  int cz = (int)floorf(p[2] + 4.0f);
  cx = min(max(cx, 0), 7);
  cy = min(max(cy, 0), 7);
  cz = min(max(cz, 0), 7);
  unsigned c = (unsigned)(cx | (cy << 3) | (cz << 6));
  unsigned r = atomicAdd(&hist[(b << 9) + c], 1u);
  rank[t] = r;
  cid[t] = c;
}

__global__ __launch_bounds__(512) void scan_kernel(const unsigned* __restrict__ hist,
                                                   unsigned* __restrict__ starts) {
  __shared__ unsigned a[512];
  int b = blockIdx.x, t = threadIdx.x;
  unsigned h = hist[(b << 9) + t];
  a[t] = h;
  __syncthreads();
  for (int s = 1; s < 512; s <<= 1) {
    unsigned v = (t >= s) ? a[t - s] : 0u;
    __syncthreads();
    a[t] += v;
    __syncthreads();
  }
  starts[(b << 9) + t] = a[t] - h;  // exclusive
}

__global__ __launch_bounds__(256) void scatter_kernel(
    const float* __restrict__ xyz, const unsigned* __restrict__ starts,
    const unsigned* __restrict__ rank, const unsigned* __restrict__ cid,
    float* __restrict__ xs2, float* __restrict__ ys2, float* __restrict__ zs2,
    unsigned* __restrict__ oi2) {
  int t = blockIdx.x * 256 + threadIdx.x;
  int b = t >> 14, n = t & 16383;
  unsigned pos = starts[(b << 9) + cid[t]] + rank[t];
  const float* p = xyz + (size_t)t * 3;
  size_t o = ((size_t)b << 14) + pos;
  xs2[o] = p[0];
  ys2[o] = p[1];
  zs2[o] = p[2];
  oi2[o] = (unsigned)n;
}

// ---------------- FPS: one block (1024 thr) per batch, 16 SORTED pts/thread --
// Points are grid-sorted so each thread's 16 contiguous points are spatially
// tight -> per-thread bbox skip test: if lb(c, bbox)*0.999 >= tv (chunk max
// min_d), NO min_d in the chunk can change (d2 >= lb >= tv >= min_d[p]) ->
// skip the sweep EXACTLY (M, tv unchanged). x,y in LDS (thread-private
// slots); z, M, origidx OI, bbox in regs. Tie-break is exact under any
// permutation: reduce (max val, min ORIGINAL idx): DPP val max -> readlane ->
// matching lanes chunk-min-OI (regs only, exec-masked) -> DPP u32 min ->
// lane63 writes {val,oi} slot (it&1 double-buffer, plain stores, no reset)
// -> ONE barrier -> 16-slot shfl max/min butterfly -> j -> uniform coord
// load from ORIGINAL xyz. Skip-safety: 0.999 factor makes f32 rounding
// strictly conservative. tv invariant: tv == max(M) always (skips don't
// change M; sweeps recompute tv).
__global__ __launch_bounds__(1024) void fps_kernel(
    const float* __restrict__ xyz, const float* __restrict__ xs,
    const float* __restrict__ ys, const float* __restrict__ zs,
    const unsigned* __restrict__ oi, int* __restrict__ idx_out) {
#pragma clang fp contract(off)
  extern __shared__ float4 xylds[];  // 8192 entries = 128 KB
  __shared__ unsigned s_wval[2][16];
  __shared__ unsigned s_woi[2][16];
  int b = blockIdx.x;
  int tid = threadIdx.x;
  int lane = tid & 63, wid = tid >> 6;
  const float* xb = xyz + (size_t)b * 16384 * 3;
  int base = tid << 4;  // 16 consecutive sorted slots
  const float4* xv = (const float4*)(xs + ((size_t)b << 14) + base);
  const float4* yv = (const float4*)(ys + ((size_t)b << 14) + base);
  const float4* zv = (const float4*)(zs + ((size_t)b << 14) + base);
  const uint4* ov = (const uint4*)(oi + ((size_t)b << 14) + base);
  float xr[16], yr[16], zr[16];
  unsigned OI[16];
#pragma unroll
  for (int q = 0; q < 4; ++q) {
    *(float4*)(xr + 4 * q) = xv[q];
    *(float4*)(yr + 4 * q) = yv[q];
    *(float4*)(zr + 4 * q) = zv[q];
    *(uint4*)(OI + 4 * q) = ov[q];
  }
  // per-thread bbox of its 16 points
  float bxl = xr[0], bxh = xr[0], byl = yr[0], byh = yr[0], bzl = zr[0],
        bzh = zr[0];
#pragma unroll
  for (int k = 1; k < 16; ++k) {
    bxl = fminf(bxl, xr[k]); bxh = fmaxf(bxh, xr[k]);
    byl = fminf(byl, yr[k]); byh = fmaxf(byh, yr[k]);
    bzl = fminf(bzl, zr[k]); bzh = fmaxf(bzh, zr[k]);
  }
  f32x2 Z[8], M[8];
#pragma unroll
  for (int q = 0; q < 8; ++q) {
    xylds[(q << 10) + tid] =
        make_float4(xr[2 * q], xr[2 * q + 1], yr[2 * q], yr[2 * q + 1]);
    Z[q] = {zr[2 * q], zr[2 * q + 1]};
    M[q] = {__builtin_inff(), __builtin_inff()};
  }
  if (tid == 0) idx_out[b * 1024] = 0;
  __syncthreads();
  float px = xb[0], py = xb[1], pz = xb[2];
  float tv = __builtin_inff();  // invariant: tv == max(M)
  for (int it = 1; it < 1024; ++it) {
    int sl = it & 1;
    // ---- bbox skip test (conservative: 0.999 shrink)
    float ddx = fmaxf(fmaxf(bxl - px, px - bxh), 0.0f);
    float ddy = fmaxf(fmaxf(byl - py, py - byh), 0.0f);
    float ddz = fmaxf(fmaxf(bzl - pz, pz - bzh), 0.0f);
    float lb = (ddx * ddx + ddy * ddy + ddz * ddz) * 0.999f;
    if (lb < tv) {
      // ---- packed sweep: native f32x2, no FMA (contract off)
      f32x2 px2 = {px, px}, py2 = {py, py}, pz2 = {pz, pz};
      float ntv = -1.0f;
#pragma unroll
      for (int q = 0; q < 8; ++q) {
        float4 t = xylds[(q << 10) + tid];  // {x0,x1,y0,y1}
        f32x2 X = {t.x, t.y};
        f32x2 Y = {t.z, t.w};
        f32x2 dx = X - px2;
        f32x2 dy = Y - py2;
        f32x2 dz = Z[q] - pz2;
        f32x2 d = dx * dx + dy * dy + dz * dz;  // RN each op, ref order
        M[q].x = fminf(M[q].x, d.x);
        M[q].y = fminf(M[q].y, d.y);
        ntv = fmaxf(fmaxf(ntv, M[q].x), M[q].y);
      }
      tv = ntv;
    }
    // ---- wave candidate: DPP value max, matching lanes reduce origidx
    float bv = wave64_max_dpp(tv);
    unsigned bvb = (unsigned)__builtin_amdgcn_readlane(__float_as_int(bv), 63);
    float bvf = __int_as_float((int)bvb);
    unsigned coi = 0xffffffffu;
    if (tv == bvf) {  // rare; register-only rescan (full min, order-free)
#pragma unroll
      for (int q = 0; q < 8; ++q) {
        if (M[q].x == bvf && OI[2 * q] < coi) coi = OI[2 * q];
        if (M[q].y == bvf && OI[2 * q + 1] < coi) coi = OI[2 * q + 1];
      }
    }
    unsigned woi = wave64_min_dpp_u32(coi);
    if (lane == 63) {
      s_wval[sl][wid] = bvb;
      s_woi[sl][wid] = woi;
    }
    __syncthreads();  // the only barrier
    // ---- block winner: max val, then min origidx among achieving waves
    unsigned w0 = s_wval[sl][lane & 15];
    unsigned o0 = s_woi[sl][lane & 15];
    unsigned v = w0;
#pragma unroll
    for (int off = 1; off <= 8; off <<= 1) {
      unsigned ov_ = __shfl_xor(v, off);
      v = (ov_ > v) ? ov_ : v;
    }
    unsigned cand = (w0 == v) ? o0 : 0xffffffffu;
#pragma unroll
    for (int off = 1; off <= 8; off <<= 1) {
      unsigned oc = __shfl_xor(cand, off);
      cand = (oc < cand) ? oc : cand;
    }
    int j = (int)cand;
    if (tid == 0) idx_out[b * 1024 + it] = j;
    // uniform address -> cache broadcast (original AoS xyz)
    px = xb[j * 3 + 0];
    py = xb[j * 3 + 1];
    pz = xb[j * 3 + 2];
  }
}

// ---------------- gather new_xyz into d_out[0 .. 24576) ----------------------
__global__ __launch_bounds__(256) void gather_newxyz(const float* __restrict__ xyz,
                                                     const int* __restrict__ idx,
                                                     float* __restrict__ out) {
  int t = blockIdx.x * 256 + threadIdx.x;  // 0..8191 = (b,p)
  int b = t >> 10;
  int i = idx[t];
  const float* src = xyz + ((size_t)b * 16384 + i) * 3;
  float* dst = out + (size_t)t * 3;
  dst[0] = src[0];
  dst[1] = src[1];
  dst[2] = src[2];
}

// ---------------- transpose features (B,64,N) -> (B,N,64) --------------------
__global__ __launch_bounds__(256) void transpose_feats(const float* __restrict__ f,
                                                       float* __restrict__ fT) {
  __shared__ float tile[64][65];
  int b = blockIdx.x >> 8;
  int n0 = (blockIdx.x & 255) << 6;
  int t = threadIdx.x;
  int nn = t & 63, c0 = t >> 6;
#pragma unroll
  for (int r = 0; r < 64; r += 4) {
    int c = c0 + r;
    tile[c][nn] = f[((size_t)b * 64 + c) * 16384 + n0 + nn];
  }
  __syncthreads();
  int cc = t & 63, n1 = t >> 6;
#pragma unroll
  for (int r = 0; r < 64; r += 4) {
    int n = n1 + r;
    fT[((size_t)b * 16384 + n0 + n) * 64 + cc] = tile[cc][n];
  }
}

// ---------------- ball query: one wave per centroid --------------------------
__global__ __launch_bounds__(256) void ballquery_kernel(const float* __restrict__ xyz,
                                                        const float* __restrict__ newxyz,
                                                        int* __restrict__ gidx) {
  int wid = threadIdx.x >> 6, lane = threadIdx.x & 63;
  int cid = blockIdx.x * 4 + wid;  // 0..8191
  int b = cid >> 10;
  const float* xb = xyz + (size_t)b * 16384 * 3;
  float cx = newxyz[cid * 3 + 0];
  float cy = newxyz[cid * 3 + 1];
  float cz = newxyz[cid * 3 + 2];
  int* out = gidx + (size_t)cid * 32;
  int found = 0;
  int first = -1;
  for (int c0 = 0; c0 < 16384; c0 += 64) {
    int g = c0 + lane;
    float xx = xb[g * 3 + 0], yy = xb[g * 3 + 1], zz = xb[g * 3 + 2];
    float d2 = sqd(xx, yy, zz, cx, cy, cz);
    bool inr = (d2 <= R2);
    unsigned long long mask = __ballot(inr);
    if (first < 0 && mask) first = c0 + (int)__builtin_ctzll(mask);
    int pre = __popcll(mask & ((1ull << lane) - 1ull));
    int slot = found + pre;
    if (inr && slot < 32) out[slot] = g;
    found += __popcll(mask);
    if (found >= 32) break;
  }
  for (int s = found + lane; s < 32; s += 64) out[s] = first;
}

// ---------------- fused group + MLP(67->64->64->128) + maxpool ---------------
#define FMA16(BASEPTR)                                                     \
  do {                                                                     \
    const float4* hp_ = (const float4*)(BASEPTR);                          \
    float4 v0 = hp_[0], v1 = hp_[1], v2 = hp_[2], v3 = hp_[3];             \
    float a = acc[s];                                                      \
    a = fmaf(w[0], v0.x, a);  a = fmaf(w[1], v0.y, a);                     \
    a = fmaf(w[2], v0.z, a);  a = fmaf(w[3], v0.w, a);                     \
    a = fmaf(w[4], v1.x, a);  a = fmaf(w[5], v1.y, a);                     \
    a = fmaf(w[6], v1.z, a);  a = fmaf(w[7], v1.w, a);                     \
    a = fmaf(w[8], v2.x, a);  a = fmaf(w[9], v2.y, a);                     \
    a = fmaf(w[10], v2.z, a); a = fmaf(w[11], v2.w, a);                    \
    a = fmaf(w[12], v3.x, a); a = fmaf(w[13], v3.y, a);                    \
    a = fmaf(w[14], v3.z, a); a = fmaf(w[15], v3.w, a);                    \
    acc[s] = a;                                                            \
  } while (0)

__global__ __launch_bounds__(256) void mlp_kernel(
    const float* __restrict__ xyz, const float* __restrict__ feats,
    const float* __restrict__ featsT, const float* __restrict__ newxyz,
    const int* __restrict__ gidx,
    const float* __restrict__ W1, const float* __restrict__ b1,
    const float* __restrict__ W2, const float* __restrict__ b2,
    const float* __restrict__ W3, const float* __restrict__ b3,
    float* __restrict__ out, int useT) {
  __shared__ float buf[4][32 * 68];
  int wid = threadIdx.x >> 6, lane = threadIdx.x & 63;
  int cid = blockIdx.x * 4 + wid;
  int b = cid >> 10, p = cid & 1023;
  float* A = buf[wid];
  const int* gi = gidx + (size_t)cid * 32;
  float cx = newxyz[cid * 3 + 0];
  float cy = newxyz[cid * 3 + 1];
  float cz = newxyz[cid * 3 + 2];

  // ---- stage h0
  if (useT) {
    const float4* fT4 = (const float4*)(featsT + (size_t)b * 16384 * 64);
    for (int t = lane; t < 512; t += 64) {
      int s = t >> 4, q = t & 15;
      int g = gi[s];
      float4 v = fT4[(size_t)g * 16 + q];
      *(float4*)(A + s * 68 + q * 4) = v;
    }
  } else {
    const float* fb = feats + (size_t)b * 64 * 16384;
    for (int t = lane; t < 2048; t += 64) {
      int c = t >> 5, s = t & 31;
      int g = gi[s];
      A[s * 68 + c] = fb[(size_t)c * 16384 + g];
    }
  }
  for (int t = lane; t < 96; t += 64) {
    int s = t / 3, c = t - s * 3;
    int g = gi[s];
    float pv = xyz[((size_t)b * 16384 + g) * 3 + c];
    float cv = (c == 0) ? cx : ((c == 1) ? cy : cz);
    A[s * 68 + 64 + c] = __fsub_rn(pv, cv);
  }
  if (lane < 32) A[lane * 68 + 67] = 0.0f;
  __syncthreads();

  int o = lane;
  float acc[32];

  // ---- L1: 67 -> 64
#pragma unroll
  for (int s = 0; s < 32; ++s) acc[s] = b1[o];
  {
    const float* wr = W1 + o * 67;
    for (int cb = 0; cb < 4; ++cb) {
      float w[16];
#pragma unroll
      for (int q = 0; q < 16; ++q) w[q] = wr[3 + cb * 16 + q];
#pragma unroll
      for (int s = 0; s < 32; ++s) { FMA16(A + s * 68 + cb * 16); }
    }
    float w0 = wr[0], w1 = wr[1], w2 = wr[2];
#pragma unroll
    for (int s = 0; s < 32; ++s) {
      float a = acc[s];
      a = fmaf(w0, A[s * 68 + 64], a);
      a = fmaf(w1, A[s * 68 + 65], a);
      a = fmaf(w2, A[s * 68 + 66], a);
      acc[s] = a;
    }
  }
  __syncthreads();
#pragma unroll
  for (int s = 0; s < 32; ++s) A[s * 64 + o] = fmaxf(acc[s], 0.0f);
  __syncthreads();

  // ---- L2: 64 -> 64
#pragma unroll
  for (int s = 0; s < 32; ++s) acc[s] = b2[o];
  {
    const float* wr = W2 + o * 64;
    for (int cb = 0; cb < 4; ++cb) {
      float w[16];
#pragma unroll
      for (int q = 0; q < 16; ++q) w[q] = wr[cb * 16 + q];
#pragma unroll
      for (int s = 0; s < 32; ++s) { FMA16(A + s * 64 + cb * 16); }
    }
  }
  __syncthreads();
#pragma unroll
  for (int s = 0; s < 32; ++s) A[s * 64 + o] = fmaxf(acc[s], 0.0f);
  __syncthreads();

  // ---- L3: 64 -> 128, fused relu + maxpool over s
  float* outp = out + 24576;
  for (int po = 0; po < 2; ++po) {
    int o2 = lane + (po << 6);
#pragma unroll
    for (int s = 0; s < 32; ++s) acc[s] = b3[o2];
    const float* wr = W3 + o2 * 64;
    for (int cb = 0; cb < 4; ++cb) {
      float w[16];
#pragma unroll
      for (int q = 0; q < 16; ++q) w[q] = wr[cb * 16 + q];
#pragma unroll
      for (int s = 0; s < 32; ++s) { FMA16(A + s * 64 + cb * 16); }
    }
    float mx = 0.0f;  // relu floor
#pragma unroll
    for (int s = 0; s < 32; ++s) mx = fmaxf(mx, acc[s]);
    outp[((size_t)b * 128 + o2) * 1024 + p] = mx;
  }
}

extern "C" void kernel_launch(void* const* d_in, const int* in_sizes, int n_in,
                              void* d_out, int out_size, void* d_ws, size_t ws_size,
                              hipStream_t stream) {
  const float* xyz = (const float*)d_in[0];
  const float* feats = (const float*)d_in[1];
  const float* W1 = (const float*)d_in[2];
  const float* b1 = (const float*)d_in[3];
  const float* W2 = (const float*)d_in[4];
  const float* b2 = (const float*)d_in[5];
  const float* W3 = (const float*)d_in[6];
  const float* b3 = (const float*)d_in[7];
  float* out = (float*)d_out;

  // ws layout (bytes):
  char* w = (char*)d_ws;
  int* idx = (int*)w;                              // 32 KB
  int* gidx = (int*)(w + 32768);                   // 1 MB
  unsigned* hist = (unsigned*)(w + 1081344);       // 16 KB (8*512)
  unsigned* starts = (unsigned*)(w + 1097728);     // 16 KB
  unsigned* rank = (unsigned*)(w + 1114112);       // 512 KB
  unsigned* cid = (unsigned*)(w + 1638400);        // 512 KB
  unsigned* oi2 = (unsigned*)(w + 2162688);        // 512 KB
  float* xs2 = (float*)(w + 2686976);              // 512 KB
  float* ys2 = (float*)(w + 3211264);              // 512 KB
  float* zs2 = (float*)(w + 3735552);              // 512 KB
  float* featsT = (float*)(w + 4259840);           // 32 MB (optional)
  size_t needT = 4259840 + (size_t)8 * 16384 * 64 * sizeof(float);
  int useT = (ws_size >= needT) ? 1 : 0;

  zero_hist<<<16, 256, 0, stream>>>(hist);
  hist_kernel<<<512, 256, 0, stream>>>(xyz, hist, rank, cid);
  scan_kernel<<<8, 512, 0, stream>>>(hist, starts);
  scatter_kernel<<<512, 256, 0, stream>>>(xyz, starts, rank, cid, xs2, ys2,
                                          zs2, oi2);
  fps_kernel<<<8, 1024, 131072, stream>>>(xyz, xs2, ys2, zs2, oi2, idx);
  gather_newxyz<<<32, 256, 0, stream>>>(xyz, idx, out);
  if (useT) transpose_feats<<<2048, 256, 0, stream>>>(feats, featsT);
  ballquery_kernel<<<2048, 256, 0, stream>>>(xyz, out, gidx);
  mlp_kernel<<<2048, 256, 0, stream>>>(xyz, feats, featsT, out, gidx,
                                       W1, b1, W2, b2, W3, b3, out, useT);
}